// Round 8
// baseline (162.116 us; speedup 1.0000x reference)
//
#include <hip/hip_runtime.h>
#include <hip/hip_bf16.h>

// Problem constants
#define S_LEN   4096
#define D_MOD   512
#define BATCH   4
#define HALF_W  128
#define M_TOT   (BATCH * S_LEN)   // 16384

typedef __attribute__((ext_vector_type(8))) short bf16x8;
typedef __attribute__((ext_vector_type(4))) float f32x4;

__device__ __forceinline__ unsigned short f2bf(float f) {
    // round-to-nearest-even bf16 (values are finite here)
    unsigned int u = __float_as_uint(f);
    unsigned int r = (u + 0x7fffu + ((u >> 16) & 1u)) >> 16;
    return (unsigned short)r;
}

__device__ __forceinline__ void async_copy16(const void* g, void* l) {
    __builtin_amdgcn_global_load_lds(
        (const __attribute__((address_space(1))) void*)g,
        (__attribute__((address_space(3))) void*)l, 16, 0, 0);
}

// ---------------------------------------------------------------------------
// Kernel 1: fused converts (byte-identical).
__global__ __launch_bounds__(256) void convert_xw(const float* __restrict__ x,
                                                  const float* __restrict__ Wq,
                                                  const float* __restrict__ Wk,
                                                  const float* __restrict__ Wv,
                                                  unsigned short* __restrict__ xb,
                                                  unsigned short* __restrict__ Wt) {
    __shared__ float sT[64][65];
    const int t = threadIdx.x;
    const int bid = blockIdx.x;
    if (bid < 8192) {
        int i = (bid * 256 + t) * 4;
        float4 v = *(const float4*)(x + i);
        ushort4 o;
        o.x = f2bf(v.x); o.y = f2bf(v.y); o.z = f2bf(v.z); o.w = f2bf(v.w);
        *(ushort4*)(xb + i) = o;
        return;
    }
    const int j = bid - 8192;            // 0..191
    const int w = j >> 6;                // weight select (64 tiles each)
    const int rj = j & 63;
    const float* W = (w == 0) ? Wq : ((w == 1) ? Wk : Wv);
    const int n0 = (rj & 7) * 64, k0 = (rj >> 3) * 64;
    const int r = t >> 4, c4 = (t & 15) * 4;
    #pragma unroll
    for (int i = 0; i < 4; ++i) {
        float4 v = *(const float4*)(W + (size_t)(k0 + r + i * 16) * 512 + n0 + c4);
        sT[c4 + 0][r + i * 16] = v.x;
        sT[c4 + 1][r + i * 16] = v.y;
        sT[c4 + 2][r + i * 16] = v.z;
        sT[c4 + 3][r + i * 16] = v.w;
    }
    __syncthreads();
    #pragma unroll
    for (int i = 0; i < 4; ++i) {
        int rr = (t >> 4) + i * 16;   // n-local
        ushort4 o;
        o.x = f2bf(sT[rr][c4 + 0]);
        o.y = f2bf(sT[rr][c4 + 1]);
        o.z = f2bf(sT[rr][c4 + 2]);
        o.w = f2bf(sT[rr][c4 + 3]);
        *(ushort4*)(Wt + (size_t)w * 262144 + (size_t)(n0 + rr) * 512 + k0 + c4) = o;
    }
}

// ---------------------------------------------------------------------------
// Kernel 2: fused QKV GEMM — v3 (byte-identical to r7's passing version).
__global__ __launch_bounds__(512, 1) void qkv_gemm(
    const unsigned short* __restrict__ xb, const unsigned short* __restrict__ Wt,
    const float* __restrict__ bq, const float* __restrict__ bk, const float* __restrict__ bv,
    unsigned short* __restrict__ Qo, unsigned short* __restrict__ Ko,
    unsigned short* __restrict__ Vt) {
    __shared__ __align__(16) char gsmem[98304];
    unsigned short* const sA0 = (unsigned short*)gsmem;             // [256][64], chunk-swizzled
    unsigned short* const sA1 = (unsigned short*)(gsmem + 32768);
    unsigned short* const sB0 = (unsigned short*)(gsmem + 65536);   // [128][64]
    unsigned short* const sB1 = (unsigned short*)(gsmem + 81920);
    unsigned short* const sT  = (unsigned short*)gsmem;             // epilogue alias

    const int t = threadIdx.x;
    // XCD swizzle over 768 blocks (= 8 * 96)
    const int p = blockIdx.x;
    const int l = (p & 7) * 96 + (p >> 3);
    const int mi = l / 12;               // 0..63
    const int rzn = l - mi * 12;
    const int wsel = rzn >> 2;
    const int ni = rzn & 3;
    const int m0 = mi * 256;
    const int n0 = ni * 128;
    const unsigned short* Wb = Wt + (size_t)wsel * 262144;

    const int w = t >> 6, lane = t & 63;
    const int wm = (w & 3) * 64, wn = (w >> 2) * 64;
    const int qd = lane >> 4, l16 = lane & 15;

    f32x4 acc[4][4] = {};

    // prologue: stage k0=0 into buf0 (A: 4 chunks/thread, B: 2 chunks/thread)
    #pragma unroll
    for (int i = 0; i < 4; ++i) {
        int c = i * 512 + t;
        int row = c >> 3, cc = c & 7;
        int g = cc ^ (row & 7);                       // source-chunk permute
        async_copy16(xb + (size_t)(m0 + row) * 512 + g * 8, sA0 + c * 8);
    }
    #pragma unroll
    for (int i = 0; i < 2; ++i) {
        int c = i * 512 + t;
        int row = c >> 3, cc = c & 7;
        int g = cc ^ (row & 7);
        async_copy16(Wb + (size_t)(n0 + row) * 512 + g * 8, sB0 + c * 8);
    }
    __syncthreads();   // buf0 ready (vmcnt(0) drained by syncthreads semantics)

    int cur = 0;
    for (int k0 = 0; k0 < 512; k0 += 64) {
        // (1) stage NEXT K-tile into buf^1 (latency covered by compute below)
        if (k0 + 64 < 512) {
            unsigned short* dA = cur ? sA0 : sA1;
            unsigned short* dB = cur ? sB0 : sB1;
            int k0n = k0 + 64;
            #pragma unroll
            for (int i = 0; i < 4; ++i) {
                int c = i * 512 + t;
                int row = c >> 3, cc = c & 7;
                int g = cc ^ (row & 7);
                async_copy16(xb + (size_t)(m0 + row) * 512 + k0n + g * 8, dA + c * 8);
            }
            #pragma unroll
            for (int i = 0; i < 2; ++i) {
                int c = i * 512 + t;
                int row = c >> 3, cc = c & 7;
                int g = cc ^ (row & 7);
                async_copy16(Wb + (size_t)(n0 + row) * 512 + k0n + g * 8, dB + c * 8);
            }
        }

        // (2) compute current buf
        const unsigned short* sA = cur ? sA1 : sA0;
        const unsigned short* sB = cur ? sB1 : sB0;
        #pragma unroll
        for (int ks = 0; ks < 2; ++ks) {
            bf16x8 af[4], bfr[4];
            #pragma unroll
            for (int i = 0; i < 4; ++i) {
                int row = wm + i * 16 + l16;
                int ch = (ks * 4 + qd) ^ (row & 7);       // logical chunk ks*4+qd
                af[i] = *(const bf16x8*)(sA + row * 64 + ch * 8);
            }
            #pragma unroll
            for (int j = 0; j < 4; ++j) {
                int row = wn + j * 16 + l16;
                int ch = (ks * 4 + qd) ^ (row & 7);
                bfr[j] = *(const bf16x8*)(sB + row * 64 + ch * 8);
            }
            #pragma unroll
            for (int i = 0; i < 4; ++i)
                #pragma unroll
                for (int j = 0; j < 4; ++j)
                    acc[i][j] = __builtin_amdgcn_mfma_f32_16x16x32_bf16(af[i], bfr[j], acc[i][j], 0, 0, 0);
        }

        // (3) single barrier per step: prefetch arrived (covered), buf reusable
        __syncthreads();
        cur ^= 1;
    }

    const float* bias = (wsel == 0) ? bq : ((wsel == 1) ? bk : bv);
    // loop ended with __syncthreads(); sT alias safe

    if (wsel < 2) {
        // sT[m][n'] rows 256, stride 136 (16B-aligned: 272 B)
        #pragma unroll
        for (int j = 0; j < 4; ++j) {
            int n = wn + j * 16 + l16;
            float bj = bias[n0 + n];
            #pragma unroll
            for (int i = 0; i < 4; ++i) {
                int mb = wm + i * 16 + qd * 4;
                #pragma unroll
                for (int r = 0; r < 4; ++r)
                    sT[(mb + r) * 136 + n] = f2bf(acc[i][j][r] + bj);
            }
        }
        __syncthreads();
        unsigned short* Og = (wsel == 0) ? Qo : Ko;
        #pragma unroll
        for (int i2 = 0; i2 < 4; ++i2)
            #pragma unroll
            for (int i3 = 0; i3 < 2; ++i3) {
                int m = i2 * 64 + (t >> 3);               // 0..255
                int ch = (t & 7) + i3 * 8;                // 0..15
                bf16x8 v = *(const bf16x8*)(sT + m * 136 + ch * 8);
                *(bf16x8*)(Og + (size_t)(m0 + m) * 512 + n0 + ch * 8) = v;
            }
    } else {
        // sT[n][m'] rows 128, stride 264 (16B-aligned: 528 B)
        #pragma unroll
        for (int j = 0; j < 4; ++j) {
            int n = wn + j * 16 + l16;
            float bj = bias[n0 + n];
            #pragma unroll
            for (int i = 0; i < 4; ++i) {
                int mb = wm + i * 16 + qd * 4;
                #pragma unroll
                for (int r = 0; r < 4; ++r)
                    sT[n * 264 + mb + r] = f2bf(acc[i][j][r] + bj);
            }
        }
        __syncthreads();
        #pragma unroll
        for (int i2 = 0; i2 < 2; ++i2)
            #pragma unroll
            for (int i3 = 0; i3 < 4; ++i3) {
                int n = i2 * 64 + (t >> 3);               // 0..127
                int ch = (t & 7) + i3 * 8;                // 0..31
                bf16x8 v = *(const bf16x8*)(sT + n * 264 + ch * 8);
                *(bf16x8*)(Vt + (size_t)(n0 + n) * M_TOT + m0 + ch * 8) = v;
            }
    }
}

// ---------------------------------------------------------------------------
// Kernel 3: banded attention — v5: v4b structure with REG-STAGED K/V
// (plain global loads -> VGPR one tile ahead; vmcnt(0)+ds_write after PV).
// Hypothesis: global_load_lds delivery (~7 B/cy/CU) was the per-tile floor;
// the plain-load path measured ~13 B/cy/CU (r1). Everything else identical:
// q64 tile, LDS dbuf, 2 barriers/tile, V source-swizzle, 520-padded K.
__global__ __launch_bounds__(512, 2) void attn(const unsigned short* __restrict__ Qg,
                                               const unsigned short* __restrict__ Kg,
                                               const unsigned short* __restrict__ Vt,
                                               float* __restrict__ out) {
    // LDS arena (137,472 B): bufK0 @0 (33,280) | bufV0 @33,280 (32,768)
    //  bufK1 @66,048 (33,280) | bufV1 @99,328 (32,768)
    //  sQ [64][512] @66,048 (65,536; overlays buf1, prologue only)
    //  sP [64][40] @132,096 (5,120) | lsum[64] @137,216 (256)
    __shared__ __align__(16) char smem[137472];
    unsigned short* const bK0 = (unsigned short*)(smem);
    unsigned short* const bK1 = (unsigned short*)(smem + 66048);
    unsigned short* const bV0 = (unsigned short*)(smem + 33280);
    unsigned short* const bV1 = (unsigned short*)(smem + 99328);
    unsigned short* const sQ  = (unsigned short*)(smem + 66048);
    unsigned short* const sP  = (unsigned short*)(smem + 132096);
    float* const lsum = (float*)(smem + 137216);

    const int t = threadIdx.x;
    // XCD swizzle over 256 blocks: l = (p&7)*32 + p/8
    const int p = blockIdx.x;
    const int l = (p & 7) * 32 + (p >> 3);
    const int q0 = (l & 63) * 64;        // query offset within batch
    const int b = l >> 6;
    const int bS = b * S_LEN;

    const int w = t >> 6, lane = t & 63;
    const int qd = lane >> 4, l16 = lane & 15;
    const int qs = w >> 1;               // q-sub 0..3 (16 rows each)
    const int qh = qs * 16;
    const int kh = (w & 1) * 16;         // QK key-half
    const int dh = (w & 1) * 256;        // PV d-half

    if (t < 64) lsum[t] = 0.f;

    // key-tile range
    const int kt_lo = (q0 < 128) ? ((128 - q0) >> 5) : 0;
    int kt_hi = (4192 - q0) >> 5;
    if (kt_hi > 9) kt_hi = 9;

    bf16x8 qreg[16], kreg[4], vreg[4];
    f32x4 oacc[16] = {};   // [dt]

    // ---- K/V load helpers (per-thread 4 chunks each) ----
    // K: c = i*512+t -> row=c>>6 (uniform per wave-instr), cc=c&63
    // V: c = i*512+t -> rp=c>>3, chs=c&7; logical ch = chs^(rp&7)

    // ---- prologue ----
    {
        int key0 = q0 - HALF_W + kt_lo * 32;
        // issue K(lo), V(lo) -> regs
        #pragma unroll
        for (int i = 0; i < 4; ++i) {
            int c = i * 512 + t;
            int row = c >> 6, cc = c & 63;
            int rowg = key0 + row;
            rowg = (rowg < 0) ? 0 : ((rowg > S_LEN - 1) ? S_LEN - 1 : rowg);
            kreg[i] = *(const bf16x8*)(Kg + (size_t)(bS + rowg) * 512 + cc * 8);
        }
        #pragma unroll
        for (int i = 0; i < 4; ++i) {
            int c = i * 512 + t;
            int rp = c >> 3, chs = c & 7;
            int ch = chs ^ (rp & 7);
            int d = rp * 2 + (ch >> 2);
            int kc = ch & 3;
            int kk = key0 + kc * 8;
            int koff = (kk >= 0 && kk + 8 <= S_LEN) ? kk : 0;   // clamped, masked via P=0
            vreg[i] = *(const bf16x8*)(Vt + (size_t)d * M_TOT + bS + koff);
        }
        // stage Q [64][512] into sQ (buf1 overlay), source chunk-swizzled
        #pragma unroll
        for (int i = 0; i < 8; ++i) {
            int c = i * 512 + t;
            int row = c >> 6, cc = c & 63;
            int g = cc ^ (row & 7);
            async_copy16(Qg + (size_t)(bS + q0 + row) * 512 + g * 8, sQ + row * 512 + cc * 8);
        }
    }
    asm volatile("s_waitcnt vmcnt(0)" ::: "memory");   // Q staged + K/V(lo) regs arrived
    __builtin_amdgcn_s_barrier();
    // Q fragments to registers (physical chunk = logical ^ (row&7))
    #pragma unroll
    for (int c4 = 0; c4 < 4; ++c4)
        #pragma unroll
        for (int kc = 0; kc < 4; ++kc) {
            int chl = c4 * 16 + kc * 4 + qd;
            int chp = chl ^ (l16 & 7);
            qreg[c4 * 4 + kc] = *(const bf16x8*)(sQ + (qh + l16) * 512 + chp * 8);
        }
    asm volatile("s_waitcnt lgkmcnt(0)" ::: "memory");  // qreg done before buf1 reuse
    __builtin_amdgcn_s_barrier();

    // ds_write K(lo),V(lo) -> buf0; issue K(lo+1),V(lo+1) -> regs
    #pragma unroll
    for (int i = 0; i < 4; ++i) {
        int c = i * 512 + t;
        int row = c >> 6, cc = c & 63;
        *(bf16x8*)(bK0 + row * 520 + cc * 8) = kreg[i];
    }
    #pragma unroll
    for (int i = 0; i < 4; ++i) {
        int c = i * 512 + t;
        *(bf16x8*)(bV0 + c * 8) = vreg[i];
    }
    {
        int key0n = q0 - HALF_W + (kt_lo + 1) * 32;
        #pragma unroll
        for (int i = 0; i < 4; ++i) {
            int c = i * 512 + t;
            int row = c >> 6, cc = c & 63;
            int rowg = key0n + row;
            rowg = (rowg < 0) ? 0 : ((rowg > S_LEN - 1) ? S_LEN - 1 : rowg);
            kreg[i] = *(const bf16x8*)(Kg + (size_t)(bS + rowg) * 512 + cc * 8);
        }
        #pragma unroll
        for (int i = 0; i < 4; ++i) {
            int c = i * 512 + t;
            int rp = c >> 3, chs = c & 7;
            int ch = chs ^ (rp & 7);
            int d = rp * 2 + (ch >> 2);
            int kc = ch & 3;
            int kk = key0n + kc * 8;
            int koff = (kk >= 0 && kk + 8 <= S_LEN) ? kk : 0;
            vreg[i] = *(const bf16x8*)(Vt + (size_t)d * M_TOT + bS + koff);
        }
    }
    asm volatile("s_waitcnt lgkmcnt(0)" ::: "memory");  // buf0 writes visible
    __builtin_amdgcn_s_barrier();

    // ---- main loop: entry invariant: buf[cur] = K/V(kt); regs = K/V(kt+1) in flight
    int cur = 0;
    for (int kt = kt_lo; kt <= kt_hi; ++kt, cur ^= 1) {
        const int key0 = q0 - HALF_W + kt * 32;
        const unsigned short* sK = cur ? bK1 : bK0;
        const unsigned short* sV = cur ? bV1 : bV0;

        // (c) QK: S[16q][16k-half] over full D
        f32x4 sacc = {0.f, 0.f, 0.f, 0.f};
        #pragma unroll
        for (int c4 = 0; c4 < 4; ++c4) {
            #pragma unroll
            for (int kc = 0; kc < 4; ++kc) {
                bf16x8 bk8 = *(const bf16x8*)(sK + (kh + l16) * 520 + c4 * 128 + kc * 32 + qd * 8);
                sacc = __builtin_amdgcn_mfma_f32_16x16x32_bf16(qreg[c4 * 4 + kc], bk8, sacc, 0, 0, 0);
            }
        }
        // mask + exp + write P + row sums
        const float scale = 0.04419417382415922f;   // 1/sqrt(512)
        #pragma unroll
        for (int r = 0; r < 4; ++r) {
            int qi = q0 + qh + qd * 4 + r;
            int kj = key0 + kh + l16;
            bool valid = (kj >= 0) && (kj < S_LEN) && (kj >= qi - HALF_W) && (kj <= qi + HALF_W);
            float p2 = valid ? __expf(sacc[r] * scale) : 0.f;
            sP[(qh + qd * 4 + r) * 40 + kh + l16] = f2bf(p2);
            float s = p2;
            s += __shfl_xor(s, 1);
            s += __shfl_xor(s, 2);
            s += __shfl_xor(s, 4);
            s += __shfl_xor(s, 8);
            if (l16 == 0) atomicAdd(&lsum[qh + qd * 4 + r], s);
        }

        // (d) sP visible to PV (cross-wave)
        asm volatile("s_waitcnt lgkmcnt(0)" ::: "memory");
        __builtin_amdgcn_s_barrier();

        // (e) PV: O[16q][256d-half] += P . V  (swizzled V reads)
        bf16x8 ap = *(const bf16x8*)(sP + (qh + l16) * 40 + qd * 8);
        #pragma unroll
        for (int dt = 0; dt < 16; ++dt) {
            int dv = dh + dt * 16 + l16;
            int rp = dv >> 1;
            int chs = (((dv & 1) << 2) + qd) ^ (rp & 7);
            bf16x8 bv8 = *(const bf16x8*)(sV + rp * 64 + chs * 8);
            oacc[dt] = __builtin_amdgcn_mfma_f32_16x16x32_bf16(ap, bv8, oacc[dt], 0, 0, 0);
        }

        // (f) publish K/V(kt+1) from regs into buf^1; issue loads for kt+2
        if (kt < kt_hi) {
            unsigned short* dK = cur ? bK0 : bK1;
            unsigned short* dV = cur ? bV0 : bV1;
            asm volatile("s_waitcnt vmcnt(0)" ::: "memory");   // regs arrived (full-tile cover)
            #pragma unroll
            for (int i = 0; i < 4; ++i) {
                int c = i * 512 + t;
                int row = c >> 6, cc = c & 63;
                *(bf16x8*)(dK + row * 520 + cc * 8) = kreg[i];
            }
            #pragma unroll
            for (int i = 0; i < 4; ++i) {
                int c = i * 512 + t;
                *(bf16x8*)(dV + c * 8) = vreg[i];
            }
            if (kt + 2 <= kt_hi) {
                int key0n = key0 + 64;
                #pragma unroll
                for (int i = 0; i < 4; ++i) {
                    int c = i * 512 + t;
                    int row = c >> 6, cc = c & 63;
                    int rowg = key0n + row;
                    rowg = (rowg < 0) ? 0 : ((rowg > S_LEN - 1) ? S_LEN - 1 : rowg);
                    kreg[i] = *(const bf16x8*)(Kg + (size_t)(bS + rowg) * 512 + cc * 8);
                }
                #pragma unroll
                for (int i = 0; i < 4; ++i) {
                    int c = i * 512 + t;
                    int rp = c >> 3, chs = c & 7;
                    int ch = chs ^ (rp & 7);
                    int d = rp * 2 + (ch >> 2);
                    int kc = ch & 3;
                    int kk = key0n + kc * 8;
                    int koff = (kk >= 0 && kk + 8 <= S_LEN) ? kk : 0;
                    vreg[i] = *(const bf16x8*)(Vt + (size_t)d * M_TOT + bS + koff);
                }
            }
        }

        // (a') all ds_writes visible; PV reads of buf[cur] done by all waves
        asm volatile("s_waitcnt lgkmcnt(0)" ::: "memory");
        __builtin_amdgcn_s_barrier();
    }

    // ---- epilogue
    float inv[4];
    #pragma unroll
    for (int r = 0; r < 4; ++r)
        inv[r] = 1.0f / lsum[qh + qd * 4 + r];

    #pragma unroll
    for (int dt = 0; dt < 16; ++dt) {
        int dv = dh + dt * 16 + l16;
        #pragma unroll
        for (int r = 0; r < 4; ++r) {
            int q = qh + qd * 4 + r;
            out[(size_t)(bS + q0 + q) * 512 + dv] = oacc[dt][r] * inv[r];
        }
    }
}

// ---------------------------------------------------------------------------
extern "C" void kernel_launch(void* const* d_in, const int* in_sizes, int n_in,
                              void* d_out, int out_size, void* d_ws, size_t ws_size,
                              hipStream_t stream) {
    const float* x  = (const float*)d_in[0];
    const float* Wq = (const float*)d_in[1];
    const float* bq = (const float*)d_in[2];
    const float* Wk = (const float*)d_in[3];
    const float* bk = (const float*)d_in[4];
    const float* Wv = (const float*)d_in[5];
    const float* bv = (const float*)d_in[6];
    float* out = (float*)d_out;

    char* ws = (char*)d_ws;
    unsigned short* xb = (unsigned short*)(ws);                    // 16 MB
    unsigned short* Wt = (unsigned short*)(ws + 16777216);         // 1.5 MB
    unsigned short* Qb = (unsigned short*)(ws + 18350080);         // 16 MB
    unsigned short* Kb = (unsigned short*)(ws + 35127296);         // 16 MB
    unsigned short* Vt = (unsigned short*)(ws + 51904512);         // 16 MB, [512][16384]

    convert_xw<<<8384, 256, 0, stream>>>(x, Wq, Wk, Wv, xb, Wt);
    qkv_gemm<<<768, 512, 0, stream>>>(xb, Wt, bq, bk, bv, Qb, Kb, Vt);
    attn<<<256, 512, 0, stream>>>(Qb, Kb, Vt, out);
}

// Round 10
// 157.084 us; speedup vs baseline: 1.0320x; 1.0320x over previous
//
#include <hip/hip_runtime.h>
#include <hip/hip_bf16.h>

// Problem constants
#define S_LEN   4096
#define D_MOD   512
#define BATCH   4
#define HALF_W  128
#define M_TOT   (BATCH * S_LEN)   // 16384

typedef __attribute__((ext_vector_type(8))) short bf16x8;
typedef __attribute__((ext_vector_type(4))) float f32x4;

__device__ __forceinline__ unsigned short f2bf(float f) {
    // round-to-nearest-even bf16 (values are finite here)
    unsigned int u = __float_as_uint(f);
    unsigned int r = (u + 0x7fffu + ((u >> 16) & 1u)) >> 16;
    return (unsigned short)r;
}

__device__ __forceinline__ void async_copy16(const void* g, void* l) {
    __builtin_amdgcn_global_load_lds(
        (const __attribute__((address_space(1))) void*)g,
        (__attribute__((address_space(3))) void*)l, 16, 0, 0);
}

// ---------------------------------------------------------------------------
// Kernel 1: fused converts (byte-identical).
__global__ __launch_bounds__(256) void convert_xw(const float* __restrict__ x,
                                                  const float* __restrict__ Wq,
                                                  const float* __restrict__ Wk,
                                                  const float* __restrict__ Wv,
                                                  unsigned short* __restrict__ xb,
                                                  unsigned short* __restrict__ Wt) {
    __shared__ float sT[64][65];
    const int t = threadIdx.x;
    const int bid = blockIdx.x;
    if (bid < 8192) {
        int i = (bid * 256 + t) * 4;
        float4 v = *(const float4*)(x + i);
        ushort4 o;
        o.x = f2bf(v.x); o.y = f2bf(v.y); o.z = f2bf(v.z); o.w = f2bf(v.w);
        *(ushort4*)(xb + i) = o;
        return;
    }
    const int j = bid - 8192;            // 0..191
    const int w = j >> 6;                // weight select (64 tiles each)
    const int rj = j & 63;
    const float* W = (w == 0) ? Wq : ((w == 1) ? Wk : Wv);
    const int n0 = (rj & 7) * 64, k0 = (rj >> 3) * 64;
    const int r = t >> 4, c4 = (t & 15) * 4;
    #pragma unroll
    for (int i = 0; i < 4; ++i) {
        float4 v = *(const float4*)(W + (size_t)(k0 + r + i * 16) * 512 + n0 + c4);
        sT[c4 + 0][r + i * 16] = v.x;
        sT[c4 + 1][r + i * 16] = v.y;
        sT[c4 + 2][r + i * 16] = v.z;
        sT[c4 + 3][r + i * 16] = v.w;
    }
    __syncthreads();
    #pragma unroll
    for (int i = 0; i < 4; ++i) {
        int rr = (t >> 4) + i * 16;   // n-local
        ushort4 o;
        o.x = f2bf(sT[rr][c4 + 0]);
        o.y = f2bf(sT[rr][c4 + 1]);
        o.z = f2bf(sT[rr][c4 + 2]);
        o.w = f2bf(sT[rr][c4 + 3]);
        *(ushort4*)(Wt + (size_t)w * 262144 + (size_t)(n0 + rr) * 512 + k0 + c4) = o;
    }
}

// ---------------------------------------------------------------------------
// Kernel 2: fused QKV GEMM — v3 (byte-identical to r7's passing version).
__global__ __launch_bounds__(512, 1) void qkv_gemm(
    const unsigned short* __restrict__ xb, const unsigned short* __restrict__ Wt,
    const float* __restrict__ bq, const float* __restrict__ bk, const float* __restrict__ bv,
    unsigned short* __restrict__ Qo, unsigned short* __restrict__ Ko,
    unsigned short* __restrict__ Vt) {
    __shared__ __align__(16) char gsmem[98304];
    unsigned short* const sA0 = (unsigned short*)gsmem;             // [256][64], chunk-swizzled
    unsigned short* const sA1 = (unsigned short*)(gsmem + 32768);
    unsigned short* const sB0 = (unsigned short*)(gsmem + 65536);   // [128][64]
    unsigned short* const sB1 = (unsigned short*)(gsmem + 81920);
    unsigned short* const sT  = (unsigned short*)gsmem;             // epilogue alias

    const int t = threadIdx.x;
    // XCD swizzle over 768 blocks (= 8 * 96)
    const int p = blockIdx.x;
    const int l = (p & 7) * 96 + (p >> 3);
    const int mi = l / 12;               // 0..63
    const int rzn = l - mi * 12;
    const int wsel = rzn >> 2;
    const int ni = rzn & 3;
    const int m0 = mi * 256;
    const int n0 = ni * 128;
    const unsigned short* Wb = Wt + (size_t)wsel * 262144;

    const int w = t >> 6, lane = t & 63;
    const int wm = (w & 3) * 64, wn = (w >> 2) * 64;
    const int qd = lane >> 4, l16 = lane & 15;

    f32x4 acc[4][4] = {};

    // prologue: stage k0=0 into buf0 (A: 4 chunks/thread, B: 2 chunks/thread)
    #pragma unroll
    for (int i = 0; i < 4; ++i) {
        int c = i * 512 + t;
        int row = c >> 3, cc = c & 7;
        int g = cc ^ (row & 7);                       // source-chunk permute
        async_copy16(xb + (size_t)(m0 + row) * 512 + g * 8, sA0 + c * 8);
    }
    #pragma unroll
    for (int i = 0; i < 2; ++i) {
        int c = i * 512 + t;
        int row = c >> 3, cc = c & 7;
        int g = cc ^ (row & 7);
        async_copy16(Wb + (size_t)(n0 + row) * 512 + g * 8, sB0 + c * 8);
    }
    __syncthreads();   // buf0 ready (vmcnt(0) drained by syncthreads semantics)

    int cur = 0;
    for (int k0 = 0; k0 < 512; k0 += 64) {
        // (1) stage NEXT K-tile into buf^1 (latency covered by compute below)
        if (k0 + 64 < 512) {
            unsigned short* dA = cur ? sA0 : sA1;
            unsigned short* dB = cur ? sB0 : sB1;
            int k0n = k0 + 64;
            #pragma unroll
            for (int i = 0; i < 4; ++i) {
                int c = i * 512 + t;
                int row = c >> 3, cc = c & 7;
                int g = cc ^ (row & 7);
                async_copy16(xb + (size_t)(m0 + row) * 512 + k0n + g * 8, dA + c * 8);
            }
            #pragma unroll
            for (int i = 0; i < 2; ++i) {
                int c = i * 512 + t;
                int row = c >> 3, cc = c & 7;
                int g = cc ^ (row & 7);
                async_copy16(Wb + (size_t)(n0 + row) * 512 + k0n + g * 8, dB + c * 8);
            }
        }

        // (2) compute current buf
        const unsigned short* sA = cur ? sA1 : sA0;
        const unsigned short* sB = cur ? sB1 : sB0;
        #pragma unroll
        for (int ks = 0; ks < 2; ++ks) {
            bf16x8 af[4], bfr[4];
            #pragma unroll
            for (int i = 0; i < 4; ++i) {
                int row = wm + i * 16 + l16;
                int ch = (ks * 4 + qd) ^ (row & 7);       // logical chunk ks*4+qd
                af[i] = *(const bf16x8*)(sA + row * 64 + ch * 8);
            }
            #pragma unroll
            for (int j = 0; j < 4; ++j) {
                int row = wn + j * 16 + l16;
                int ch = (ks * 4 + qd) ^ (row & 7);
                bfr[j] = *(const bf16x8*)(sB + row * 64 + ch * 8);
            }
            #pragma unroll
            for (int i = 0; i < 4; ++i)
                #pragma unroll
                for (int j = 0; j < 4; ++j)
                    acc[i][j] = __builtin_amdgcn_mfma_f32_16x16x32_bf16(af[i], bfr[j], acc[i][j], 0, 0, 0);
        }

        // (3) single barrier per step: prefetch arrived (covered), buf reusable
        __syncthreads();
        cur ^= 1;
    }

    const float* bias = (wsel == 0) ? bq : ((wsel == 1) ? bk : bv);
    // loop ended with __syncthreads(); sT alias safe

    if (wsel < 2) {
        // sT[m][n'] rows 256, stride 136 (16B-aligned: 272 B)
        #pragma unroll
        for (int j = 0; j < 4; ++j) {
            int n = wn + j * 16 + l16;
            float bj = bias[n0 + n];
            #pragma unroll
            for (int i = 0; i < 4; ++i) {
                int mb = wm + i * 16 + qd * 4;
                #pragma unroll
                for (int r = 0; r < 4; ++r)
                    sT[(mb + r) * 136 + n] = f2bf(acc[i][j][r] + bj);
            }
        }
        __syncthreads();
        unsigned short* Og = (wsel == 0) ? Qo : Ko;
        #pragma unroll
        for (int i2 = 0; i2 < 4; ++i2)
            #pragma unroll
            for (int i3 = 0; i3 < 2; ++i3) {
                int m = i2 * 64 + (t >> 3);               // 0..255
                int ch = (t & 7) + i3 * 8;                // 0..15
                bf16x8 v = *(const bf16x8*)(sT + m * 136 + ch * 8);
                *(bf16x8*)(Og + (size_t)(m0 + m) * 512 + n0 + ch * 8) = v;
            }
    } else {
        // sT[n][m'] rows 128, stride 264 (16B-aligned: 528 B)
        #pragma unroll
        for (int j = 0; j < 4; ++j) {
            int n = wn + j * 16 + l16;
            float bj = bias[n0 + n];
            #pragma unroll
            for (int i = 0; i < 4; ++i) {
                int mb = wm + i * 16 + qd * 4;
                #pragma unroll
                for (int r = 0; r < 4; ++r)
                    sT[n * 264 + mb + r] = f2bf(acc[i][j][r] + bj);
            }
        }
        __syncthreads();
        #pragma unroll
        for (int i2 = 0; i2 < 2; ++i2)
            #pragma unroll
            for (int i3 = 0; i3 < 4; ++i3) {
                int n = i2 * 64 + (t >> 3);               // 0..127
                int ch = (t & 7) + i3 * 8;                // 0..31
                bf16x8 v = *(const bf16x8*)(sT + n * 264 + ch * 8);
                *(bf16x8*)(Vt + (size_t)(n0 + n) * M_TOT + m0 + ch * 8) = v;
            }
    }
}

// ---------------------------------------------------------------------------
// Kernel 3: banded attention — v7: merged-phase pipeline, V-race fixed.
// Phase i: {vmcnt(0)+barrier} -> issue K(i+1)->K[(i+1)&1], V(i)->V[i&1]
//          -> QK(i) (reads K[i&1], writes P[i&1]) ∥ PV(i-1) (reads V[(i-1)&1],
//          P[(i-1)&1]) -> lgkmcnt(0).
// Buffer safety per phase i: write K[(i+1)&1] vs read K[i&1] (distinct);
// write V[i&1] vs read V[(i-1)&1] (distinct); every buffer's previous reader
// finished >=1 barrier upstream. vmcnt(0) at phase top drains loads issued a
// FULL phase earlier (v4b's proven cover). ONE barrier per phase.
__global__ __launch_bounds__(512, 2) void attn(const unsigned short* __restrict__ Qg,
                                               const unsigned short* __restrict__ Kg,
                                               const unsigned short* __restrict__ Vt,
                                               float* __restrict__ out) {
    // LDS arena (142,592 B):
    //   K0 [32][520] @0        (33,280)
    //   K1 [32][520] @33,280   (33,280)
    //   V0 swz       @66,560   (32,768)
    //   V1 swz       @99,328   (32,768)
    //   sQ [64][512] @66,560   (65,536; overlays V0+V1, prologue only)
    //   P0 [64][40]  @132,096  ( 5,120)
    //   P1 [64][40]  @137,216  ( 5,120)
    //   lsum[64]     @142,336  (   256)
    __shared__ __align__(16) char smem[142592];
    unsigned short* const K0 = (unsigned short*)(smem);
    unsigned short* const K1 = (unsigned short*)(smem + 33280);
    unsigned short* const V0 = (unsigned short*)(smem + 66560);
    unsigned short* const V1 = (unsigned short*)(smem + 99328);
    unsigned short* const sQ = (unsigned short*)(smem + 66560);
    unsigned short* const P0 = (unsigned short*)(smem + 132096);
    unsigned short* const P1 = (unsigned short*)(smem + 137216);
    float* const lsum = (float*)(smem + 142336);

    const int t = threadIdx.x;
    // XCD swizzle over 256 blocks: l = (p&7)*32 + p/8
    const int p = blockIdx.x;
    const int l = (p & 7) * 32 + (p >> 3);
    const int q0 = (l & 63) * 64;        // query offset within batch
    const int b = l >> 6;
    const int bS = b * S_LEN;

    const int w = t >> 6, lane = t & 63;
    const int qd = lane >> 4, l16 = lane & 15;
    const int qh = (w >> 1) * 16;        // q-sub (16 rows)
    const int kh = (w & 1) * 16;         // QK key-half
    const int dh = (w & 1) * 256;        // PV d-half

    if (t < 64) lsum[t] = 0.f;

    // key-tile range
    const int kt_lo = (q0 < 128) ? ((128 - q0) >> 5) : 0;
    int kt_hi = (4192 - q0) >> 5;
    if (kt_hi > 9) kt_hi = 9;

    bf16x8 qreg[16];
    f32x4 oacc[16] = {};   // [dt]

    auto stageK = [&](int key0, unsigned short* dst) {
        #pragma unroll
        for (int i = 0; i < 4; ++i) {
            int c = i * 512 + t;
            int row = c >> 6, cc = c & 63;   // row uniform per wave-instr
            int rowg = key0 + row;
            rowg = (rowg < 0) ? 0 : ((rowg > S_LEN - 1) ? S_LEN - 1 : rowg);
            async_copy16(Kg + (size_t)(bS + rowg) * 512 + cc * 8, dst + row * 520 + cc * 8);
        }
    };
    auto stageV = [&](int key0, unsigned short* dst) {
        #pragma unroll
        for (int i = 0; i < 4; ++i) {
            int c = i * 512 + t;
            int rp = c >> 3, chs = c & 7;
            int ch = chs ^ (rp & 7);         // source pre-swizzle
            int d = rp * 2 + (ch >> 2);
            int kc = ch & 3;
            int kk = key0 + kc * 8;
            int koff = (kk >= 0 && kk + 8 <= S_LEN) ? kk : 0;   // clamped, masked via P=0
            async_copy16(Vt + (size_t)d * M_TOT + bS + koff, dst + c * 8);
        }
    };

    // ---- prologue: K(lo) -> K[lo&1]; Q -> sQ overlay (V area)
    stageK(q0 - HALF_W + kt_lo * 32, (kt_lo & 1) ? K1 : K0);
    #pragma unroll
    for (int i = 0; i < 8; ++i) {
        int c = i * 512 + t;
        int row = c >> 6, cc = c & 63;
        int g = cc ^ (row & 7);
        async_copy16(Qg + (size_t)(bS + q0 + row) * 512 + g * 8, sQ + row * 512 + cc * 8);
    }
    asm volatile("s_waitcnt vmcnt(0)" ::: "memory");   // Q + K(lo) staged
    __builtin_amdgcn_s_barrier();
    // Q fragments to registers (physical chunk = logical ^ (row&7))
    #pragma unroll
    for (int c4 = 0; c4 < 4; ++c4)
        #pragma unroll
        for (int kc = 0; kc < 4; ++kc) {
            int chl = c4 * 16 + kc * 4 + qd;
            int chp = chl ^ (l16 & 7);
            qreg[c4 * 4 + kc] = *(const bf16x8*)(sQ + (qh + l16) * 512 + chp * 8);
        }
    asm volatile("s_waitcnt lgkmcnt(0)" ::: "memory");  // qreg done before V overlays sQ
    __builtin_amdgcn_s_barrier();

    const float scale = 0.04419417382415922f;   // 1/sqrt(512)

    // ---- merged-phase main loop: phase i = QK(i) ∥ PV(i-1)
    for (int i = kt_lo; i <= kt_hi + 1; ++i) {
        const int key0 = q0 - HALF_W + i * 32;

        asm volatile("s_waitcnt vmcnt(0)" ::: "memory");   // K(i), V(i-1) landed
        __builtin_amdgcn_s_barrier();
        __builtin_amdgcn_sched_barrier(0);   // no LDS reads hoist above barrier

        // prefetch: K(i+1) (read next phase), V(i) (read next phase by PV(i))
        if (i + 1 <= kt_hi) stageK(key0 + 32, ((i + 1) & 1) ? K1 : K0);
        if (i <= kt_hi)     stageV(key0,      (i & 1) ? V1 : V0);

        if (i <= kt_hi) {
            // QK(i): S[16q][16k-half] over full D
            const unsigned short* sK = (i & 1) ? K1 : K0;
            f32x4 sacc = {0.f, 0.f, 0.f, 0.f};
            #pragma unroll
            for (int c4 = 0; c4 < 4; ++c4) {
                #pragma unroll
                for (int kc = 0; kc < 4; ++kc) {
                    bf16x8 bk8 = *(const bf16x8*)(sK + (kh + l16) * 520 + c4 * 128 + kc * 32 + qd * 8);
                    sacc = __builtin_amdgcn_mfma_f32_16x16x32_bf16(qreg[c4 * 4 + kc], bk8, sacc, 0, 0, 0);
                }
            }
            // mask + exp + write P[i&1] + row sums
            unsigned short* sPc = (i & 1) ? P1 : P0;
            #pragma unroll
            for (int r = 0; r < 4; ++r) {
                int qi = q0 + qh + qd * 4 + r;
                int kj = key0 + kh + l16;
                bool valid = (kj >= 0) && (kj < S_LEN) && (kj >= qi - HALF_W) && (kj <= qi + HALF_W);
                float p2 = valid ? __expf(sacc[r] * scale) : 0.f;
                sPc[(qh + qd * 4 + r) * 40 + kh + l16] = f2bf(p2);
                float s = p2;
                s += __shfl_xor(s, 1);
                s += __shfl_xor(s, 2);
                s += __shfl_xor(s, 4);
                s += __shfl_xor(s, 8);
                if (l16 == 0) atomicAdd(&lsum[qh + qd * 4 + r], s);
            }
        }

        if (i > kt_lo) {
            // PV(i-1): O[16q][256d-half] += P . V  (independent of QK above)
            const unsigned short* sV  = ((i - 1) & 1) ? V1 : V0;
            const unsigned short* sPp = ((i - 1) & 1) ? P1 : P0;
            bf16x8 ap = *(const bf16x8*)(sPp + (qh + l16) * 40 + qd * 8);
            #pragma unroll
            for (int dt = 0; dt < 16; ++dt) {
                int dv = dh + dt * 16 + l16;
                int rp = dv >> 1;
                int chs = (((dv & 1) << 2) + qd) ^ (rp & 7);
                bf16x8 bv8 = *(const bf16x8*)(sV + rp * 64 + chs * 8);
                oacc[dt] = __builtin_amdgcn_mfma_f32_16x16x32_bf16(ap, bv8, oacc[dt], 0, 0, 0);
            }
        }

        asm volatile("s_waitcnt lgkmcnt(0)" ::: "memory");   // LDS ops drained pre-barrier
    }
    __builtin_amdgcn_s_barrier();   // lsum atomics visible

    // ---- epilogue
    float inv[4];
    #pragma unroll
    for (int r = 0; r < 4; ++r)
        inv[r] = 1.0f / lsum[qh + qd * 4 + r];

    #pragma unroll
    for (int dt = 0; dt < 16; ++dt) {
        int dv = dh + dt * 16 + l16;
        #pragma unroll
        for (int r = 0; r < 4; ++r) {
            int q = qh + qd * 4 + r;
            out[(size_t)(bS + q0 + q) * 512 + dv] = oacc[dt][r] * inv[r];
        }
    }
}

// ---------------------------------------------------------------------------
extern "C" void kernel_launch(void* const* d_in, const int* in_sizes, int n_in,
                              void* d_out, int out_size, void* d_ws, size_t ws_size,
                              hipStream_t stream) {
    const float* x  = (const float*)d_in[0];
    const float* Wq = (const float*)d_in[1];
    const float* bq = (const float*)d_in[2];
    const float* Wk = (const float*)d_in[3];
    const float* bk = (const float*)d_in[4];
    const float* Wv = (const float*)d_in[5];
    const float* bv = (const float*)d_in[6];
    float* out = (float*)d_out;

    char* ws = (char*)d_ws;
    unsigned short* xb = (unsigned short*)(ws);                    // 16 MB
    unsigned short* Wt = (unsigned short*)(ws + 16777216);         // 1.5 MB
    unsigned short* Qb = (unsigned short*)(ws + 18350080);         // 16 MB
    unsigned short* Kb = (unsigned short*)(ws + 35127296);         // 16 MB
    unsigned short* Vt = (unsigned short*)(ws + 51904512);         // 16 MB, [512][16384]

    convert_xw<<<8384, 256, 0, stream>>>(x, Wq, Wk, Wv, xb, Wt);
    qkv_gemm<<<768, 512, 0, stream>>>(xb, Wt, bq, bk, bv, Qb, Kb, Vt);
    attn<<<256, 512, 0, stream>>>(Qb, Kb, Vt, out);
}